// Round 1
// baseline (209.726 us; speedup 1.0000x reference)
//
#include <hip/hip_runtime.h>

// ============================================================================
// STDP plasticity — r13: GEMM rebuilt as 256²-tile 8-phase schedule.
// Ledger (r9 best = 199.3 us): stage ~60-70 us (HBM floor 53), gemm 76 us
// (904 TF = m97-structure plateau, MfmaUtil 36%), merge 11 us, ~36 us fixed.
// r13 theory: plateau is structural (vmcnt(0) drain at every barrier). Port
// to the verified 256² 8-phase template (T2 swizzle + T3/T4 counted vmcnt +
// T5 setprio; 1563-1728 TF measured): split-K=4 -> 256 blocks x 512 thr,
// 128 KB LDS, Gray-code quadrant order, all LDS overwrites barrier-separated
// from last reads, vmcnt(2) at phases 4/8 only. Predicted gemm ~48 us,
// merge ~16 us (5 streams), total ~175 us. Fallback to r9 gemm if ws<118MB.
// Closed branches (measured): fused epilogue (r4 +126us), coop grid-sync
// (r8 capture-fail), BK=32 splitK=4@128² (r7, conflicts), fused gemm+merge
// (r10/r11 +3us), stage split (r12 +4us).
// ============================================================================

constexpr int TB = 16;        // batch
constexpr int NP = 2048;      // pre neurons
constexpr int NQ = 2048;      // post neurons
constexpr int TT = 256;       // timesteps
constexpr int KH = TB * TT;   // 4096, half-K
constexpr int KT = 2 * KH;    // 8192, total contraction length

typedef unsigned short ushort_t;
typedef __attribute__((ext_vector_type(8))) __bf16 bf16x8;
typedef __attribute__((ext_vector_type(4))) float f32x4;

// bf16 round-to-nearest-even, as uint (inputs finite)
__device__ __forceinline__ unsigned bf1(float f) {
    unsigned u = __builtin_bit_cast(unsigned, f);
    return (u + 0x7FFFu + ((u >> 16) & 1u)) >> 16;
}
__device__ __forceinline__ unsigned pack2(float lo, float hi) {
    return bf1(lo) | (bf1(hi) << 16);
}
__device__ __forceinline__ unsigned spk2(float a, float b) {
    return ((a != 0.f) ? 0x3F80u : 0u) | ((b != 0.f) ? 0x3F800000u : 0u);
}

// Decay powers
constexpr float DF1 = 0.95122942450071400910f;            // exp(-0.05)
constexpr float DF2 = DF1 * DF1;
constexpr float DF4 = DF2 * DF2;
constexpr float DF8 = DF4 * DF4;
constexpr float DF16 = DF8 * DF8;
constexpr float DF32 = DF16 * DF16;
constexpr float DF64 = DF32 * DF32;

constexpr float DX1 = 0.99014786386058731819f;            // exp(-1/101)
constexpr float DX2 = DX1 * DX1;
constexpr float DX4 = DX2 * DX2;
constexpr float DX8 = DX4 * DX4;
constexpr float DX16 = DX8 * DX8;
constexpr float DX32 = DX16 * DX16;
constexpr float DX64 = DX32 * DX32;

template <int K>
__device__ __forceinline__ float seg_step(float b, float pw, int sl) {
    float t = __shfl_up(b, K, 64);
    return (sl >= K) ? fmaf(pw, t, b) : b;
}
__device__ __forceinline__ float scan16(float c, float p1, float p2, float p4,
                                        float p8, int sl) {
    c = seg_step<1>(c, p1, sl);
    c = seg_step<2>(c, p2, sl);
    c = seg_step<4>(c, p4, sl);
    c = seg_step<8>(c, p8, sl);
    return c;
}
__device__ __forceinline__ float fold4(float4 u, float d) {
    float C = d * u.x;
    C = d * (C + u.y); C = d * (C + u.z); C = d * (C + u.w);
    return C;
}
__device__ __forceinline__ float4 expand4(float x, float4 u, float d) {
    float4 t;
    t.x = x; x = d * (x + u.x);
    t.y = x; x = d * (x + u.y);
    t.z = x; x = d * (x + u.z);
    t.w = x;
    return t;
}

// ---------------------------------------------------------------------------
// Stage 1 (unchanged from r9): slot-coalesced traces -> bf16 A/B panels.
// ---------------------------------------------------------------------------
__global__ __launch_bounds__(256) void stage_traces(
    const float* __restrict__ pre, const float* __restrict__ post,
    const float* __restrict__ mApP, const float* __restrict__ mAmP,
    ushort_t* __restrict__ Ab, ushort_t* __restrict__ Bb,
    float* __restrict__ partials)
{
    const int tid  = threadIdx.x;
    const int lane = tid & 63;
    const int wv   = tid >> 6;
    const int sl   = lane & 15;
    const int rowg = blockIdx.x * 16 + wv * 4 + (lane >> 4);   // 0..65535
    const bool isPre = rowg < TB * NP;                         // block-uniform
    const int m = isPre ? rowg : rowg - TB * NP;
    const int b = m >> 11;
    const int r = m & 2047;

    const float4* srcRow = (const float4*)((isPre ? pre : post) + (size_t)m * TT);
    const float4 u0 = srcRow[sl];          // slot 0: t = 4sl..4sl+3
    const float4 u1 = srcRow[16 + sl];     // slot 1
    const float4 u2 = srcRow[32 + sl];     // slot 2
    const float4 u3 = srcRow[48 + sl];     // slot 3

    float cnt = ((u0.x + u0.y) + (u0.z + u0.w)) + ((u1.x + u1.y) + (u1.z + u1.w))
              + ((u2.x + u2.y) + (u2.z + u2.w)) + ((u3.x + u3.y) + (u3.z + u3.w));

    const int hi = lane | 15;

    // ---- fast-decay trace: per-slot scans + cross-slot carry ----
    float bf0 = scan16(fold4(u0, DF1), DF4, DF8, DF16, DF32, sl);
    float bf1_ = scan16(fold4(u1, DF1), DF4, DF8, DF16, DF32, sl);
    float bf2 = scan16(fold4(u2, DF1), DF4, DF8, DF16, DF32, sl);
    float bf3 = scan16(fold4(u3, DF1), DF4, DF8, DF16, DF32, sl);
    const float Tf0 = __shfl(bf0, hi, 64);
    const float Tf1 = __shfl(bf1_, hi, 64);
    const float Tf2 = __shfl(bf2, hi, 64);
    const float Xf1 = Tf0;
    const float Xf2 = fmaf(DF64, Xf1, Tf1);
    const float Xf3 = fmaf(DF64, Xf2, Tf2);
    float ef0 = __shfl_up(bf0, 1, 64);
    float ef1 = __shfl_up(bf1_, 1, 64);
    float ef2 = __shfl_up(bf2, 1, 64);
    float ef3 = __shfl_up(bf3, 1, 64);
    if (sl == 0) { ef0 = 0.f; ef1 = 0.f; ef2 = 0.f; ef3 = 0.f; }
    float pf = 1.f;
    if (sl & 1) pf *= DF4;
    if (sl & 2) pf *= DF8;
    if (sl & 4) pf *= DF16;
    if (sl & 8) pf *= DF32;
    const float4 t0 = expand4(ef0,                 u0, DF1);
    const float4 t1 = expand4(fmaf(pf, Xf1, ef1),  u1, DF1);
    const float4 t2 = expand4(fmaf(pf, Xf2, ef2),  u2, DF1);
    const float4 t3 = expand4(fmaf(pf, Xf3, ef3),  u3, DF1);

    ushort_t* oA = (isPre ? Ab : Bb) + (size_t)r * KT + b * TT + 4 * sl;

    if (isPre) {
        *(uint2*)(oA)            = uint2{pack2(t0.x, t0.y), pack2(t0.z, t0.w)};
        *(uint2*)(oA + 64)       = uint2{pack2(t1.x, t1.y), pack2(t1.z, t1.w)};
        *(uint2*)(oA + 128)      = uint2{pack2(t2.x, t2.y), pack2(t2.z, t2.w)};
        *(uint2*)(oA + 192)      = uint2{pack2(t3.x, t3.y), pack2(t3.z, t3.w)};
        *(uint2*)(oA + KH)       = uint2{spk2(u0.x, u0.y), spk2(u0.z, u0.w)};
        *(uint2*)(oA + KH + 64)  = uint2{spk2(u1.x, u1.y), spk2(u1.z, u1.w)};
        *(uint2*)(oA + KH + 128) = uint2{spk2(u2.x, u2.y), spk2(u2.z, u2.w)};
        *(uint2*)(oA + KH + 192) = uint2{spk2(u3.x, u3.y), spk2(u3.z, u3.w)};
    } else {
        // ---- slow (triplet) trace ----
        float bx0 = scan16(fold4(u0, DX1), DX4, DX8, DX16, DX32, sl);
        float bx1 = scan16(fold4(u1, DX1), DX4, DX8, DX16, DX32, sl);
        float bx2 = scan16(fold4(u2, DX1), DX4, DX8, DX16, DX32, sl);
        float bx3 = scan16(fold4(u3, DX1), DX4, DX8, DX16, DX32, sl);
        const float Tx0 = __shfl(bx0, hi, 64);
        const float Tx1 = __shfl(bx1, hi, 64);
        const float Tx2 = __shfl(bx2, hi, 64);
        const float Xx1 = Tx0;
        const float Xx2 = fmaf(DX64, Xx1, Tx1);
        const float Xx3 = fmaf(DX64, Xx2, Tx2);
        float ex0 = __shfl_up(bx0, 1, 64);
        float ex1 = __shfl_up(bx1, 1, 64);
        float ex2 = __shfl_up(bx2, 1, 64);
        float ex3 = __shfl_up(bx3, 1, 64);
        if (sl == 0) { ex0 = 0.f; ex1 = 0.f; ex2 = 0.f; ex3 = 0.f; }
        float px = 1.f;
        if (sl & 1) px *= DX4;
        if (sl & 2) px *= DX8;
        if (sl & 4) px *= DX16;
        if (sl & 8) px *= DX32;
        const float4 w0 = expand4(ex0,                u0, DX1);
        const float4 w1 = expand4(fmaf(px, Xx1, ex1), u1, DX1);
        const float4 w2 = expand4(fmaf(px, Xx2, ex2), u2, DX1);
        const float4 w3 = expand4(fmaf(px, Xx3, ex3), u3, DX1);

        const float Ap = *mApP;
        const float Am = *mAmP;
        auto av2 = [&](float sa, float ta, float sb, float tb) -> unsigned {
            unsigned lo = (sa != 0.f) ? bf1(fmaf(0.0065f, ta, Ap)) : 0u;
            unsigned hi2 = (sb != 0.f) ? bf1(fmaf(0.0065f, tb, Ap)) : 0u;
            return lo | (hi2 << 16);
        };
        *(uint2*)(oA)       = uint2{av2(u0.x, w0.x, u0.y, w0.y), av2(u0.z, w0.z, u0.w, w0.w)};
        *(uint2*)(oA + 64)  = uint2{av2(u1.x, w1.x, u1.y, w1.y), av2(u1.z, w1.z, u1.w, w1.w)};
        *(uint2*)(oA + 128) = uint2{av2(u2.x, w2.x, u2.y, w2.y), av2(u2.z, w2.z, u2.w, w2.w)};
        *(uint2*)(oA + 192) = uint2{av2(u3.x, w3.x, u3.y, w3.y), av2(u3.z, w3.z, u3.w, w3.w)};
        *(uint2*)(oA + KH)       = uint2{pack2(-Am * t0.x, -Am * t0.y), pack2(-Am * t0.z, -Am * t0.w)};
        *(uint2*)(oA + KH + 64)  = uint2{pack2(-Am * t1.x, -Am * t1.y), pack2(-Am * t1.z, -Am * t1.w)};
        *(uint2*)(oA + KH + 128) = uint2{pack2(-Am * t2.x, -Am * t2.y), pack2(-Am * t2.z, -Am * t2.w)};
        *(uint2*)(oA + KH + 192) = uint2{pack2(-Am * t3.x, -Am * t3.y), pack2(-Am * t3.z, -Am * t3.w)};
    }

    #pragma unroll
    for (int off = 32; off > 0; off >>= 1)
        cnt += __shfl_down(cnt, off, 64);
    __shared__ float wsum[4];
    if (lane == 0) wsum[wv] = cnt;
    __syncthreads();
    if (tid == 0)
        partials[blockIdx.x] = (wsum[0] + wsum[1]) + (wsum[2] + wsum[3]);
}

// ---------------------------------------------------------------------------
// async global->LDS, 16B per lane, wave-contiguous dest.
// ---------------------------------------------------------------------------
__device__ __forceinline__ void async16(const ushort_t* g, ushort_t* l) {
    __builtin_amdgcn_global_load_lds(
        (const __attribute__((address_space(1))) unsigned int*)g,
        (__attribute__((address_space(3))) unsigned int*)l,
        16, 0, 0);
}

// ---------------------------------------------------------------------------
// Stage 2 (NEW): 256x256-tile, BK=64, 8-wave, 8-phase schedule, split-K=4.
// 256 blocks x 512 threads = 1 block/CU, 128 KB LDS double-buffer.
// Per iter: 2 K-tiles, 8 phases. Phase = {ds_read frags (Gray-code quadrant
// reuse: 12/4/8/4 reads) | 1 half-tile global_load_lds prefetch -> barrier ->
// lgkmcnt(0) -> setprio(1)+16 MFMA+setprio(0) -> barrier}. Counted vmcnt(2)
// at phases 4/8 only. All LDS overwrites are barrier-separated from the
// region's last read (verified half-by-half). Same XOR slot swizzle as r9
// (0 bank conflicts measured) via pre-swizzled global src + linear LDS dest.
// ---------------------------------------------------------------------------
#define FENCE() asm volatile("" ::: "memory")
#define BAR()   do { FENCE(); __builtin_amdgcn_s_barrier(); FENCE(); } while (0)
#define LGKM0() asm volatile("s_waitcnt lgkmcnt(0)" ::: "memory")
#define VMC2()  asm volatile("s_waitcnt vmcnt(2)" ::: "memory")
#define VMC0()  asm volatile("s_waitcnt vmcnt(0)" ::: "memory")

// stage one 128-row half-tile (2 x async16/thread = 16 KB w/ 512 threads)
#define STAGE(GP, LP, KI, H) do {                                           \
    const ushort_t* _g = (GP) + (size_t)(H) * 128 * KT + (size_t)(KI) * 64; \
    ushort_t* _l = (LP) + (H) * 8192;                                       \
    async16(_g + ofG,  _l + ld0);                                           \
    async16(_g + ofG2, _l + ld1);                                           \
} while (0)

#define RD_A(BUF, QM) do {                                                  \
    _Pragma("unroll")                                                       \
    for (int mi = 0; mi < 4; ++mi) {                                        \
        const ushort_t* _r = &As[BUF][aBase + (QM) * 4096 + mi * 1024];     \
        af[mi][0] = *(const bf16x8*)(_r + sK0);                             \
        af[mi][1] = *(const bf16x8*)(_r + sK1);                             \
    }                                                                       \
} while (0)

#define RD_B(BUF, QN, BV) do {                                              \
    _Pragma("unroll")                                                       \
    for (int ni = 0; ni < 2; ++ni) {                                        \
        const ushort_t* _r = &Bs[BUF][bBase + (QN) * 2048 + ni * 1024];     \
        BV[ni][0] = *(const bf16x8*)(_r + sK0);                             \
        BV[ni][1] = *(const bf16x8*)(_r + sK1);                             \
    }                                                                       \
} while (0)

#define MFMAQ(QM, QN, BV) do {                                              \
    __builtin_amdgcn_s_setprio(1);                                          \
    _Pragma("unroll")                                                       \
    for (int ks = 0; ks < 2; ++ks)                                          \
        _Pragma("unroll")                                                   \
        for (int mi = 0; mi < 4; ++mi)                                      \
            _Pragma("unroll")                                               \
            for (int ni = 0; ni < 2; ++ni)                                  \
                acc[(QM)*4+mi][(QN)*2+ni] =                                 \
                    __builtin_amdgcn_mfma_f32_16x16x32_bf16(                \
                        af[mi][ks], BV[ni][ks],                             \
                        acc[(QM)*4+mi][(QN)*2+ni], 0, 0, 0);                \
    __builtin_amdgcn_s_setprio(0);                                          \
} while (0)

__global__ __launch_bounds__(512) void gemm8(
    const ushort_t* __restrict__ Ab, const ushort_t* __restrict__ Bb,
    const float* __restrict__ sp, float* __restrict__ scaleBuf,
    float* __restrict__ P0, float* __restrict__ P1,
    float* __restrict__ P2, float* __restrict__ P3)
{
    __shared__ ushort_t As[2][256 * 64];   // 64 KB
    __shared__ ushort_t Bs[2][256 * 64];   // 64 KB
    __shared__ float red[8];

    const int tid  = threadIdx.x;
    const int lane = tid & 63;
    const int wv   = tid >> 6;       // 0..7
    const int wr   = wv >> 2;        // 0..1 (M)
    const int wc   = wv & 3;         // 0..3 (N)
    const int quad = lane >> 4;
    const int m16  = lane & 15;

    // block 0: reduce the 4096 spike-count partials -> scale
    if (blockIdx.x == 0) {
        float v = 0.f;
        #pragma unroll
        for (int i = 0; i < 8; ++i) v += sp[tid + i * 512];
        #pragma unroll
        for (int off = 32; off > 0; off >>= 1)
            v += __shfl_down(v, off, 64);
        if (lane == 0) red[wv] = v;
        __syncthreads();
        if (tid == 0) {
            float s = ((red[0] + red[1]) + (red[2] + red[3]))
                    + ((red[4] + red[5]) + (red[6] + red[7]));
            scaleBuf[0] = sqrtf(0.1f / (s * (1.0f / 4096.0f) + 1e-6f));
        }
    }

    // XCD swizzle: 8x8 tiles x 4 z over 256 blocks; each XCD owns a 2x4
    // contiguous (pt,qt) patch (A reused 4x, B 2x inside one L2).
    const int id  = blockIdx.x;
    const int xcd = id & 7;
    const int j   = id >> 3;          // 0..31
    const int z   = j & 3;            // split-K quarter
    const int t   = j >> 2;           // 0..7
    const int pt  = ((xcd >> 1) << 1) | (t >> 2);   // 0..7
    const int qt  = ((xcd & 1) << 2) | (t & 3);     // 0..7
    const int p0  = pt * 256;
    const int q0  = qt * 256;
    const int kbase = z * (KT / 4);   // 2048 per z

    const ushort_t* Agp = Ab + (size_t)p0 * KT + kbase;
    const ushort_t* Bgp = Bb + (size_t)q0 * KT + kbase;
    const int rIn  = tid >> 3;        // 0..63
    const int rIn2 = rIn + 64;
    const size_t ofG  = (size_t)rIn  * KT + (size_t)((((tid & 7) ^ (rIn  & 7))) * 8);
    const size_t ofG2 = (size_t)rIn2 * KT + (size_t)((((tid & 7) ^ (rIn2 & 7))) * 8);
    const int ld0 = tid * 8;          // LDS element dest, rows 0..63 of half
    const int ld1 = 4096 + tid * 8;   // rows 64..127 of half

    // LDS read addressing (row&7 == m16&7 for every fragment row)
    const int x8  = (m16 & 7) * 8;
    const int sK0 = (quad * 8) ^ x8;          // ks=0 slot offset (elements)
    const int sK1 = ((quad + 4) * 8) ^ x8;    // ks=1
    const int aBase = (wr * 128 + m16) * 64;
    const int bBase = (wc * 64 + m16) * 64;

    f32x4 acc[8][4] = {};
    bf16x8 af[4][2], bv0[2][2], bv1[2][2];

    // ---- prologue: K-tile 0 (all 4 halves) + A0 of K-tile 1; vmcnt(2)
    // leaves only A0(1) in flight -> K-tile 0 landed.
    STAGE(Agp, As[0], 0, 0);
    STAGE(Agp, As[0], 0, 1);
    STAGE(Bgp, Bs[0], 0, 0);
    STAGE(Bgp, Bs[0], 0, 1);
    STAGE(Agp, As[1], 1, 0);
    VMC2();
    BAR();

    #pragma unroll 1
    for (int it = 0; it < 16; ++it) {
        const int k2 = 2 * it;
        // phase 1 — buf0 Q(0,0); prefetch A1,B0 of K-tile k2+1 (buf1 slots
        // last read at p7/p8 of previous iter — barrier-separated).
        RD_A(0, 0);
        RD_B(0, 0, bv0);
        STAGE(Agp, As[1], k2 + 1, 1);
        STAGE(Bgp, Bs[1], k2 + 1, 0);
        BAR(); LGKM0();
        MFMAQ(0, 0, bv0);
        BAR();
        // phase 2 — Q(0,1); prefetch B1(k2+1)
        RD_B(0, 1, bv1);
        STAGE(Bgp, Bs[1], k2 + 1, 1);
        BAR(); LGKM0();
        MFMAQ(0, 1, bv1);
        BAR();
        // phase 3 — Q(1,1)  (A buf0 last read here)
        RD_A(0, 1);
        BAR(); LGKM0();
        MFMAQ(1, 1, bv1);
        BAR();
        // phase 4 — Q(1,0); prefetch A0(k2+2) into just-freed As[0] half0;
        // vmcnt(2): everything through p2 landed -> K-tile k2+1 complete.
        RD_B(0, 0, bv0);
        if (it < 15) STAGE(Agp, As[0], k2 + 2, 0);
        BAR(); LGKM0();
        MFMAQ(1, 0, bv0);
        if (it < 15) { VMC2(); } else { VMC0(); }
        BAR();
        // phase 5 — buf1 Q(0,0); prefetch A1,B0(k2+2)
        RD_A(1, 0);
        RD_B(1, 0, bv0);
        if (it < 15) { STAGE(Agp, As[0], k2 + 2, 1); STAGE(Bgp, Bs[0], k2 + 2, 0); }
        BAR(); LGKM0();
        MFMAQ(0, 0, bv0);
        BAR();
        // phase 6 — Q(0,1); prefetch B1(k2+2)
        RD_B(1, 1, bv1);
        if (it < 15) STAGE(Bgp, Bs[0], k2 + 2, 1);
        BAR(); LGKM0();
        MFMAQ(0, 1, bv1);
        BAR();
        // phase 7 — Q(1,1)  (A buf1 last read here)
        RD_A(1, 1);
        BAR(); LGKM0();
        MFMAQ(1, 1, bv1);
        BAR();
        // phase 8 — Q(1,0); prefetch A0(k2+3); vmcnt(2): K-tile k2+2 landed
        // before next-iter phase 1 reads buf0.
        RD_B(1, 0, bv0);
        if (it < 15) STAGE(Agp, As[1], k2 + 3, 0);
        BAR(); LGKM0();
        MFMAQ(1, 0, bv0);
        if (it < 15) { VMC2(); }
        BAR();
    }

    float* P = (z == 0) ? P0 : ((z == 1) ? P1 : ((z == 2) ? P2 : P3));
    #pragma unroll
    for (int m = 0; m < 8; ++m) {
        const int prow = p0 + wr * 128 + m * 16 + quad * 4;
        #pragma unroll
        for (int n = 0; n < 4; ++n) {
            const int qcol = q0 + wc * 64 + n * 16 + m16;
            #pragma unroll
            for (int r = 0; r < 4; ++r)
                P[(size_t)(prow + r) * NQ + qcol] = acc[m][n][r];
        }
    }
}

// ---------------------------------------------------------------------------
// Stage 2 FALLBACK (r9, proven): split-K=2 GEMM, 512 blocks x 256 thr.
// Used only if ws_size cannot hold the 3 extra split-K partials.
// ---------------------------------------------------------------------------
__global__ __launch_bounds__(256, 2) void gemm_split(
    const ushort_t* __restrict__ Ab, const ushort_t* __restrict__ Bb,
    const float* __restrict__ sp, float* __restrict__ scaleBuf,
    float* __restrict__ P0, float* __restrict__ P1)
{
    __shared__ ushort_t Ls[2][128 * 64];
    __shared__ ushort_t Rs[2][128 * 64];
    __shared__ float red[4];

    const int tid  = threadIdx.x;
    const int lane = tid & 63;
    const int wv   = tid >> 6;
    const int wr   = wv >> 1;
    const int wc   = wv & 1;
    const int quad = lane >> 4;
    const int m16  = lane & 15;

    if (blockIdx.x == 0) {
        float v = 0.f;
        #pragma unroll
        for (int i = 0; i < 16; ++i) v += sp[tid + i * 256];
        #pragma unroll
        for (int off = 32; off > 0; off >>= 1)
            v += __shfl_down(v, off, 64);
        if (lane == 0) red[wv] = v;
        __syncthreads();
        if (tid == 0) {
            float s = (red[0] + red[1]) + (red[2] + red[3]);
            scaleBuf[0] = sqrtf(0.1f / (s * (1.0f / 4096.0f) + 1e-6f));
        }
    }

    const int id  = blockIdx.x;
    const int xcd = id & 7;
    const int j5  = id >> 3;
    const int z   = j5 & 1;
    const int t   = j5 >> 1;
    const int pt  = ((xcd >> 1) << 2) + (t >> 3);
    const int qt  = ((xcd & 1) << 3) + (t & 7);

    const int p0 = pt * 128;
    const int q0 = qt * 128;
    const int kbase = z * (KT / 2);
    const int ldsbase = wv * 512;

    const ushort_t* gaP[4];
    const ushort_t* gbP[4];
    #pragma unroll
    for (int rr = 0; rr < 4; ++rr) {
        const int c   = rr * 256 + tid;
        const int row = c >> 3;
        const int kk8 = (c & 7) ^ (row & 7);
        gaP[rr] = Ab + (size_t)(p0 + row) * KT + kbase + kk8 * 8;
        gbP[rr] = Bb + (size_t)(q0 + row) * KT + kbase + kk8 * 8;
    }

    f32x4 acc[4][4] = {};

    auto stageF = [&](int buf) {
        #pragma unroll
        for (int rr = 0; rr < 4; ++rr) {
            async16(gaP[rr], &Ls[buf][rr * 2048 + ldsbase]);
            async16(gbP[rr], &Rs[buf][rr * 2048 + ldsbase]);
            gaP[rr] += 64;
            gbP[rr] += 64;
        }
    };
    auto computeF = [&](int buf) {
        #pragma unroll
        for (int ks = 0; ks < 2; ++ks) {
            bf16x8 afl[4], bfr[4];
            #pragma unroll
            for (int i = 0; i < 4; ++i) {
                const int row  = wr * 64 + i * 16 + m16;
                const int slot = (ks * 4 + quad) ^ (row & 7);
                afl[i] = *(const bf16x8*)&Ls[buf][row * 64 + slot * 8];
            }
            #pragma unroll
            for (int jj = 0; jj < 4; ++jj) {
                const int row  = wc * 64 + jj * 16 + m16;
                const int slot = (ks * 4 + quad) ^ (row & 7);
                bfr[jj] = *(const bf16x8*)&Rs[buf][row * 64 + slot * 8];
            }
            #pragma unroll
            for (int i = 0; i < 4; ++i)
                #pragma unroll
                for (int jj = 0; jj < 4; ++jj)
                    acc[i][jj] = __builtin_amdgcn_mfma_f32_16x16x32_bf16(
                        afl[i], bfr[jj], acc[i][jj], 0, 0, 0);
        }
    };

    constexpr int NIT = (KT / 2) / 64;
    stageF(0);
    for (int kt2 = 0; kt2 < NIT / 2; ++kt2) {
        __syncthreads();
        stageF(1);
        computeF(0);
        __syncthreads();
        if (kt2 + 1 < NIT / 2)
            stageF(0);
        computeF(1);
    }

    float* P = z ? P1 : P0;
    #pragma unroll
    for (int i = 0; i < 4; ++i) {
        const int prow = p0 + wr * 64 + i * 16 + quad * 4;
        #pragma unroll
        for (int jj = 0; jj < 4; ++jj) {
            const int qcol = q0 + wc * 64 + jj * 16 + m16;
            #pragma unroll
            for (int r2 = 0; r2 < 4; ++r2)
                P[(size_t)(prow + r2) * NQ + qcol] = acc[i][jj][r2];
        }
    }
}

// ---------------------------------------------------------------------------
// Stage 3: Out = clip(W + scale*(P0+P1+P2+P3), -2, 2); P0 lives in d_out.
// ---------------------------------------------------------------------------
__global__ __launch_bounds__(256) void merge_out4(
    const float* __restrict__ W, const float* __restrict__ P1,
    const float* __restrict__ P2, const float* __restrict__ P3,
    const float* __restrict__ scaleBuf, float* __restrict__ Out)
{
    const float scale = scaleBuf[0];
    const size_t i4 = (size_t)blockIdx.x * 256 + threadIdx.x;
    float4 w = ((const float4*)W)[i4];
    float4 a = ((const float4*)Out)[i4];
    float4 b = ((const float4*)P1)[i4];
    float4 c = ((const float4*)P2)[i4];
    float4 d = ((const float4*)P3)[i4];
    float4 o;
    o.x = fminf(fmaxf(fmaf(scale, (a.x + b.x) + (c.x + d.x), w.x), -2.f), 2.f);
    o.y = fminf(fmaxf(fmaf(scale, (a.y + b.y) + (c.y + d.y), w.y), -2.f), 2.f);
    o.z = fminf(fmaxf(fmaf(scale, (a.z + b.z) + (c.z + d.z), w.z), -2.f), 2.f);
    o.w = fminf(fmaxf(fmaf(scale, (a.w + b.w) + (c.w + d.w), w.w), -2.f), 2.f);
    ((float4*)Out)[i4] = o;
}

__global__ __launch_bounds__(256) void merge_out2(
    const float* __restrict__ W, const float* __restrict__ P1,
    const float* __restrict__ scaleBuf, float* __restrict__ Out)
{
    const float scale = scaleBuf[0];
    const size_t i4 = (size_t)blockIdx.x * 256 + threadIdx.x;
    float4 w = ((const float4*)W)[i4];
    float4 a = ((const float4*)Out)[i4];
    float4 c = ((const float4*)P1)[i4];
    float4 o;
    o.x = fminf(fmaxf(fmaf(scale, a.x + c.x, w.x), -2.f), 2.f);
    o.y = fminf(fmaxf(fmaf(scale, a.y + c.y, w.y), -2.f), 2.f);
    o.z = fminf(fmaxf(fmaf(scale, a.z + c.z, w.z), -2.f), 2.f);
    o.w = fminf(fmaxf(fmaf(scale, a.w + c.w, w.w), -2.f), 2.f);
    ((float4*)Out)[i4] = o;
}

extern "C" void kernel_launch(void* const* d_in, const int* in_sizes, int n_in,
                              void* d_out, int out_size, void* d_ws, size_t ws_size,
                              hipStream_t stream) {
    const float* pre  = (const float*)d_in[0];
    const float* post = (const float*)d_in[1];
    const float* W    = (const float*)d_in[2];
    const float* mAp  = (const float*)d_in[3];
    const float* mAm  = (const float*)d_in[4];
    float* out = (float*)d_out;

    const size_t AB = (size_t)NP * KT * 2;   // 33.55 MB per panel
    const size_t PB = (size_t)NP * NQ * 4;   // 16.78 MB per partial

    char* ws = (char*)d_ws;
    float* partials = (float*)ws;                       // 16 KB (4096 slots)
    float* scaleBuf = (float*)(ws + 16384);
    ushort_t* Ab = (ushort_t*)(ws + 32768);
    ushort_t* Bb = (ushort_t*)(ws + 32768 + AB);
    float* P1 = (float*)(ws + 32768 + 2 * AB);
    float* P2 = (float*)(ws + 32768 + 2 * AB + PB);
    float* P3 = (float*)(ws + 32768 + 2 * AB + 2 * PB);

    stage_traces<<<dim3((TB * NP + TB * NQ) / 16), dim3(256), 0, stream>>>(
        pre, post, mAp, mAm, Ab, Bb, partials);

    if (ws_size >= 32768 + 2 * AB + 3 * PB) {
        gemm8<<<dim3(256), dim3(512), 0, stream>>>(
            Ab, Bb, partials, scaleBuf, out, P1, P2, P3);
        merge_out4<<<dim3(NP * NQ / 1024), dim3(256), 0, stream>>>(
            W, P1, P2, P3, scaleBuf, out);
    } else {
        gemm_split<<<dim3(512), dim3(256), 0, stream>>>(
            Ab, Bb, partials, scaleBuf, out, P1);
        merge_out2<<<dim3(NP * NQ / 1024), dim3(256), 0, stream>>>(
            W, P1, scaleBuf, out);
    }
}

// Round 2
// 200.118 us; speedup vs baseline: 1.0480x; 1.0480x over previous
//
#include <hip/hip_runtime.h>

// ============================================================================
// STDP plasticity — r14: 8-phase GEMM with flight-7 prefetch (r13 post-mortem).
// Ledger: r9 = 199.3 us (gemm_split 76 us, 904 TF plateau). r13 8-phase port
// = 209.7 us, gemm8 78 us, MfmaUtil 32.6% — REGRESSION. Root cause: stage->
// wait flight of only 2-3 phases (< HBM latency) => both per-iter vmcnt(2)
// stalled. r14 fix: quadrant-selects-half row remap (A row = QM*128+wr*64+...,
// B row = QN*128+wc*32+...) makes every LDS half single-read (A.h0@p1,
// B.h0@p1, B.h1@p2, A.h1@p3; bv0 registers live across K-tile, no re-read);
// all 8 half-tile stages/iter issue 7 phases ahead; two vmcnt(8) per iter
// (p4/p8). ds_read 24/K-tile (was 28) => MFMA-bound balance. Predicted gemm
// ~50 us, MfmaUtil ~55%, total ~182 us.
// Closed branches (measured): fused epilogue (r4 +126us), coop grid-sync
// (r8 capture-fail), BK=32 splitK=4@128² (r7 conflicts), fused gemm+merge
// (r10/r11 +3us), stage split (r12 +4us), flight-2 8-phase (r13 +10us).
// ============================================================================

constexpr int TB = 16;        // batch
constexpr int NP = 2048;      // pre neurons
constexpr int NQ = 2048;      // post neurons
constexpr int TT = 256;       // timesteps
constexpr int KH = TB * TT;   // 4096, half-K
constexpr int KT = 2 * KH;    // 8192, total contraction length

typedef unsigned short ushort_t;
typedef __attribute__((ext_vector_type(8))) __bf16 bf16x8;
typedef __attribute__((ext_vector_type(4))) float f32x4;

// bf16 round-to-nearest-even, as uint (inputs finite)
__device__ __forceinline__ unsigned bf1(float f) {
    unsigned u = __builtin_bit_cast(unsigned, f);
    return (u + 0x7FFFu + ((u >> 16) & 1u)) >> 16;
}
__device__ __forceinline__ unsigned pack2(float lo, float hi) {
    return bf1(lo) | (bf1(hi) << 16);
}
__device__ __forceinline__ unsigned spk2(float a, float b) {
    return ((a != 0.f) ? 0x3F80u : 0u) | ((b != 0.f) ? 0x3F800000u : 0u);
}

// Decay powers
constexpr float DF1 = 0.95122942450071400910f;            // exp(-0.05)
constexpr float DF2 = DF1 * DF1;
constexpr float DF4 = DF2 * DF2;
constexpr float DF8 = DF4 * DF4;
constexpr float DF16 = DF8 * DF8;
constexpr float DF32 = DF16 * DF16;
constexpr float DF64 = DF32 * DF32;

constexpr float DX1 = 0.99014786386058731819f;            // exp(-1/101)
constexpr float DX2 = DX1 * DX1;
constexpr float DX4 = DX2 * DX2;
constexpr float DX8 = DX4 * DX4;
constexpr float DX16 = DX8 * DX8;
constexpr float DX32 = DX16 * DX16;
constexpr float DX64 = DX32 * DX32;

template <int K>
__device__ __forceinline__ float seg_step(float b, float pw, int sl) {
    float t = __shfl_up(b, K, 64);
    return (sl >= K) ? fmaf(pw, t, b) : b;
}
__device__ __forceinline__ float scan16(float c, float p1, float p2, float p4,
                                        float p8, int sl) {
    c = seg_step<1>(c, p1, sl);
    c = seg_step<2>(c, p2, sl);
    c = seg_step<4>(c, p4, sl);
    c = seg_step<8>(c, p8, sl);
    return c;
}
__device__ __forceinline__ float fold4(float4 u, float d) {
    float C = d * u.x;
    C = d * (C + u.y); C = d * (C + u.z); C = d * (C + u.w);
    return C;
}
__device__ __forceinline__ float4 expand4(float x, float4 u, float d) {
    float4 t;
    t.x = x; x = d * (x + u.x);
    t.y = x; x = d * (x + u.y);
    t.z = x; x = d * (x + u.z);
    t.w = x;
    return t;
}

// ---------------------------------------------------------------------------
// Stage 1 (unchanged from r9): slot-coalesced traces -> bf16 A/B panels.
// ---------------------------------------------------------------------------
__global__ __launch_bounds__(256) void stage_traces(
    const float* __restrict__ pre, const float* __restrict__ post,
    const float* __restrict__ mApP, const float* __restrict__ mAmP,
    ushort_t* __restrict__ Ab, ushort_t* __restrict__ Bb,
    float* __restrict__ partials)
{
    const int tid  = threadIdx.x;
    const int lane = tid & 63;
    const int wv   = tid >> 6;
    const int sl   = lane & 15;
    const int rowg = blockIdx.x * 16 + wv * 4 + (lane >> 4);   // 0..65535
    const bool isPre = rowg < TB * NP;                         // block-uniform
    const int m = isPre ? rowg : rowg - TB * NP;
    const int b = m >> 11;
    const int r = m & 2047;

    const float4* srcRow = (const float4*)((isPre ? pre : post) + (size_t)m * TT);
    const float4 u0 = srcRow[sl];          // slot 0: t = 4sl..4sl+3
    const float4 u1 = srcRow[16 + sl];     // slot 1
    const float4 u2 = srcRow[32 + sl];     // slot 2
    const float4 u3 = srcRow[48 + sl];     // slot 3

    float cnt = ((u0.x + u0.y) + (u0.z + u0.w)) + ((u1.x + u1.y) + (u1.z + u1.w))
              + ((u2.x + u2.y) + (u2.z + u2.w)) + ((u3.x + u3.y) + (u3.z + u3.w));

    const int hi = lane | 15;

    // ---- fast-decay trace: per-slot scans + cross-slot carry ----
    float bf0 = scan16(fold4(u0, DF1), DF4, DF8, DF16, DF32, sl);
    float bf1_ = scan16(fold4(u1, DF1), DF4, DF8, DF16, DF32, sl);
    float bf2 = scan16(fold4(u2, DF1), DF4, DF8, DF16, DF32, sl);
    float bf3 = scan16(fold4(u3, DF1), DF4, DF8, DF16, DF32, sl);
    const float Tf0 = __shfl(bf0, hi, 64);
    const float Tf1 = __shfl(bf1_, hi, 64);
    const float Tf2 = __shfl(bf2, hi, 64);
    const float Xf1 = Tf0;
    const float Xf2 = fmaf(DF64, Xf1, Tf1);
    const float Xf3 = fmaf(DF64, Xf2, Tf2);
    float ef0 = __shfl_up(bf0, 1, 64);
    float ef1 = __shfl_up(bf1_, 1, 64);
    float ef2 = __shfl_up(bf2, 1, 64);
    float ef3 = __shfl_up(bf3, 1, 64);
    if (sl == 0) { ef0 = 0.f; ef1 = 0.f; ef2 = 0.f; ef3 = 0.f; }
    float pf = 1.f;
    if (sl & 1) pf *= DF4;
    if (sl & 2) pf *= DF8;
    if (sl & 4) pf *= DF16;
    if (sl & 8) pf *= DF32;
    const float4 t0 = expand4(ef0,                 u0, DF1);
    const float4 t1 = expand4(fmaf(pf, Xf1, ef1),  u1, DF1);
    const float4 t2 = expand4(fmaf(pf, Xf2, ef2),  u2, DF1);
    const float4 t3 = expand4(fmaf(pf, Xf3, ef3),  u3, DF1);

    ushort_t* oA = (isPre ? Ab : Bb) + (size_t)r * KT + b * TT + 4 * sl;

    if (isPre) {
        *(uint2*)(oA)            = uint2{pack2(t0.x, t0.y), pack2(t0.z, t0.w)};
        *(uint2*)(oA + 64)       = uint2{pack2(t1.x, t1.y), pack2(t1.z, t1.w)};
        *(uint2*)(oA + 128)      = uint2{pack2(t2.x, t2.y), pack2(t2.z, t2.w)};
        *(uint2*)(oA + 192)      = uint2{pack2(t3.x, t3.y), pack2(t3.z, t3.w)};
        *(uint2*)(oA + KH)       = uint2{spk2(u0.x, u0.y), spk2(u0.z, u0.w)};
        *(uint2*)(oA + KH + 64)  = uint2{spk2(u1.x, u1.y), spk2(u1.z, u1.w)};
        *(uint2*)(oA + KH + 128) = uint2{spk2(u2.x, u2.y), spk2(u2.z, u2.w)};
        *(uint2*)(oA + KH + 192) = uint2{spk2(u3.x, u3.y), spk2(u3.z, u3.w)};
    } else {
        // ---- slow (triplet) trace ----
        float bx0 = scan16(fold4(u0, DX1), DX4, DX8, DX16, DX32, sl);
        float bx1 = scan16(fold4(u1, DX1), DX4, DX8, DX16, DX32, sl);
        float bx2 = scan16(fold4(u2, DX1), DX4, DX8, DX16, DX32, sl);
        float bx3 = scan16(fold4(u3, DX1), DX4, DX8, DX16, DX32, sl);
        const float Tx0 = __shfl(bx0, hi, 64);
        const float Tx1 = __shfl(bx1, hi, 64);
        const float Tx2 = __shfl(bx2, hi, 64);
        const float Xx1 = Tx0;
        const float Xx2 = fmaf(DX64, Xx1, Tx1);
        const float Xx3 = fmaf(DX64, Xx2, Tx2);
        float ex0 = __shfl_up(bx0, 1, 64);
        float ex1 = __shfl_up(bx1, 1, 64);
        float ex2 = __shfl_up(bx2, 1, 64);
        float ex3 = __shfl_up(bx3, 1, 64);
        if (sl == 0) { ex0 = 0.f; ex1 = 0.f; ex2 = 0.f; ex3 = 0.f; }
        float px = 1.f;
        if (sl & 1) px *= DX4;
        if (sl & 2) px *= DX8;
        if (sl & 4) px *= DX16;
        if (sl & 8) px *= DX32;
        const float4 w0 = expand4(ex0,                u0, DX1);
        const float4 w1 = expand4(fmaf(px, Xx1, ex1), u1, DX1);
        const float4 w2 = expand4(fmaf(px, Xx2, ex2), u2, DX1);
        const float4 w3 = expand4(fmaf(px, Xx3, ex3), u3, DX1);

        const float Ap = *mApP;
        const float Am = *mAmP;
        auto av2 = [&](float sa, float ta, float sb, float tb) -> unsigned {
            unsigned lo = (sa != 0.f) ? bf1(fmaf(0.0065f, ta, Ap)) : 0u;
            unsigned hi2 = (sb != 0.f) ? bf1(fmaf(0.0065f, tb, Ap)) : 0u;
            return lo | (hi2 << 16);
        };
        *(uint2*)(oA)       = uint2{av2(u0.x, w0.x, u0.y, w0.y), av2(u0.z, w0.z, u0.w, w0.w)};
        *(uint2*)(oA + 64)  = uint2{av2(u1.x, w1.x, u1.y, w1.y), av2(u1.z, w1.z, u1.w, w1.w)};
        *(uint2*)(oA + 128) = uint2{av2(u2.x, w2.x, u2.y, w2.y), av2(u2.z, w2.z, u2.w, w2.w)};
        *(uint2*)(oA + 192) = uint2{av2(u3.x, w3.x, u3.y, w3.y), av2(u3.z, w3.z, u3.w, w3.w)};
        *(uint2*)(oA + KH)       = uint2{pack2(-Am * t0.x, -Am * t0.y), pack2(-Am * t0.z, -Am * t0.w)};
        *(uint2*)(oA + KH + 64)  = uint2{pack2(-Am * t1.x, -Am * t1.y), pack2(-Am * t1.z, -Am * t1.w)};
        *(uint2*)(oA + KH + 128) = uint2{pack2(-Am * t2.x, -Am * t2.y), pack2(-Am * t2.z, -Am * t2.w)};
        *(uint2*)(oA + KH + 192) = uint2{pack2(-Am * t3.x, -Am * t3.y), pack2(-Am * t3.z, -Am * t3.w)};
    }

    #pragma unroll
    for (int off = 32; off > 0; off >>= 1)
        cnt += __shfl_down(cnt, off, 64);
    __shared__ float wsum[4];
    if (lane == 0) wsum[wv] = cnt;
    __syncthreads();
    if (tid == 0)
        partials[blockIdx.x] = (wsum[0] + wsum[1]) + (wsum[2] + wsum[3]);
}

// ---------------------------------------------------------------------------
// async global->LDS, 16B per lane, wave-contiguous dest.
// ---------------------------------------------------------------------------
__device__ __forceinline__ void async16(const ushort_t* g, ushort_t* l) {
    __builtin_amdgcn_global_load_lds(
        (const __attribute__((address_space(1))) unsigned int*)g,
        (__attribute__((address_space(3))) unsigned int*)l,
        16, 0, 0);
}

// ---------------------------------------------------------------------------
// Stage 2: 256x256-tile, BK=64, 8-wave, 8-phase, split-K=4. Flight-7 stages.
// Row remap: quadrant selects the 128-row LDS half (A row = QM*128+wr*64+
// mi*16+m16; B row = QN*128+wc*32+ni*16+m16) => each half read in exactly
// one phase (A.h0@p1, B.h0@p1, B.h1@p2, A.h1@p3; +4 for buf1); bv0 held in
// registers across the K-tile (no B.h0 re-read). Stage schedule (per iter):
// p2: A0.h0+B0.h0(k+2), p3: B0.h1(k+2), p4: A0.h1(k+2), p6: A1.h0+B1.h0(k+3),
// p7: B1.h1(k+3), p8: A1.h1(k+3) — every stage lands >= 1 barrier after its
// region's only read, and is waited 7 phases later by vmcnt(8) at p4/p8.
// ---------------------------------------------------------------------------
#define FENCE() asm volatile("" ::: "memory")
#define BAR()   do { FENCE(); __builtin_amdgcn_s_barrier(); FENCE(); } while (0)
#define LGKM0() asm volatile("s_waitcnt lgkmcnt(0)" ::: "memory")
#define VMC8()  asm volatile("s_waitcnt vmcnt(8)" ::: "memory")
#define VMC0()  asm volatile("s_waitcnt vmcnt(0)" ::: "memory")

// stage one 128-row half-tile (2 x async16/thread = 16 KB w/ 512 threads)
#define STAGE(GP, LP, KI, H) do {                                           \
    const ushort_t* _g = (GP) + (size_t)(H) * 128 * KT + (size_t)(KI) * 64; \
    ushort_t* _l = (LP) + (H) * 8192;                                       \
    async16(_g + ofG,  _l + ld0);                                           \
    async16(_g + ofG2, _l + ld1);                                           \
} while (0)

#define RD_A(BUF, QM) do {                                                  \
    _Pragma("unroll")                                                       \
    for (int mi = 0; mi < 4; ++mi) {                                        \
        const ushort_t* _r = &As[BUF][(QM) * 8192 + aBase + mi * 1024];     \
        af[mi][0] = *(const bf16x8*)(_r + sK0);                             \
        af[mi][1] = *(const bf16x8*)(_r + sK1);                             \
    }                                                                       \
} while (0)

#define RD_B(BUF, QN, BV) do {                                              \
    _Pragma("unroll")                                                       \
    for (int ni = 0; ni < 2; ++ni) {                                        \
        const ushort_t* _r = &Bs[BUF][(QN) * 8192 + bBase + ni * 1024];     \
        BV[ni][0] = *(const bf16x8*)(_r + sK0);                             \
        BV[ni][1] = *(const bf16x8*)(_r + sK1);                             \
    }                                                                       \
} while (0)

#define MFMAQ(QM, QN, BV) do {                                              \
    __builtin_amdgcn_s_setprio(1);                                          \
    _Pragma("unroll")                                                       \
    for (int ks = 0; ks < 2; ++ks)                                          \
        _Pragma("unroll")                                                   \
        for (int mi = 0; mi < 4; ++mi)                                      \
            _Pragma("unroll")                                               \
            for (int ni = 0; ni < 2; ++ni)                                  \
                acc[(QM)*4+mi][(QN)*2+ni] =                                 \
                    __builtin_amdgcn_mfma_f32_16x16x32_bf16(                \
                        af[mi][ks], BV[ni][ks],                             \
                        acc[(QM)*4+mi][(QN)*2+ni], 0, 0, 0);                \
    __builtin_amdgcn_s_setprio(0);                                          \
} while (0)

__global__ __launch_bounds__(512) void gemm8(
    const ushort_t* __restrict__ Ab, const ushort_t* __restrict__ Bb,
    const float* __restrict__ sp, float* __restrict__ scaleBuf,
    float* __restrict__ P0, float* __restrict__ P1,
    float* __restrict__ P2, float* __restrict__ P3)
{
    __shared__ ushort_t As[2][256 * 64];   // 64 KB
    __shared__ ushort_t Bs[2][256 * 64];   // 64 KB
    __shared__ float red[8];

    const int tid  = threadIdx.x;
    const int lane = tid & 63;
    const int wv   = tid >> 6;       // 0..7
    const int wr   = wv >> 2;        // 0..1 (M 64-block within half)
    const int wc   = wv & 3;         // 0..3 (N 32-block within half)
    const int quad = lane >> 4;
    const int m16  = lane & 15;

    // block 0: reduce the 4096 spike-count partials -> scale
    if (blockIdx.x == 0) {
        float v = 0.f;
        #pragma unroll
        for (int i = 0; i < 8; ++i) v += sp[tid + i * 512];
        #pragma unroll
        for (int off = 32; off > 0; off >>= 1)
            v += __shfl_down(v, off, 64);
        if (lane == 0) red[wv] = v;
        __syncthreads();
        if (tid == 0) {
            float s = ((red[0] + red[1]) + (red[2] + red[3]))
                    + ((red[4] + red[5]) + (red[6] + red[7]));
            scaleBuf[0] = sqrtf(0.1f / (s * (1.0f / 4096.0f) + 1e-6f));
        }
    }

    // XCD swizzle: 8x8 tiles x 4 z over 256 blocks; each XCD owns a 2x4
    // contiguous (pt,qt) patch (A reused 4x, B 2x inside one L2).
    const int id  = blockIdx.x;
    const int xcd = id & 7;
    const int j   = id >> 3;          // 0..31
    const int z   = j & 3;            // split-K quarter
    const int t   = j >> 2;           // 0..7
    const int pt  = ((xcd >> 1) << 1) | (t >> 2);   // 0..7
    const int qt  = ((xcd & 1) << 2) | (t & 3);     // 0..7
    const int p0  = pt * 256;
    const int q0  = qt * 256;
    const int kbase = z * (KT / 4);   // 2048 per z

    const ushort_t* Agp = Ab + (size_t)p0 * KT + kbase;
    const ushort_t* Bgp = Bb + (size_t)q0 * KT + kbase;
    const int rIn  = tid >> 3;        // 0..63
    const int rIn2 = rIn + 64;
    const size_t ofG  = (size_t)rIn  * KT + (size_t)((((tid & 7) ^ (rIn  & 7))) * 8);
    const size_t ofG2 = (size_t)rIn2 * KT + (size_t)((((tid & 7) ^ (rIn2 & 7))) * 8);
    const int ld0 = tid * 8;          // LDS element dest, rows 0..63 of half
    const int ld1 = 4096 + tid * 8;   // rows 64..127 of half

    // LDS read addressing (row&7 == m16&7 for every fragment row)
    const int x8  = (m16 & 7) * 8;
    const int sK0 = (quad * 8) ^ x8;          // ks=0 slot offset (elements)
    const int sK1 = ((quad + 4) * 8) ^ x8;    // ks=1
    const int aBase = (wr * 64 + m16) * 64;
    const int bBase = (wc * 32 + m16) * 64;

    f32x4 acc[8][4] = {};
    bf16x8 af[4][2], bv0[2][2], bv1[2][2];

    // ---- prologue: stage K-tiles 0 (buf0) and 1 (buf1) fully; vmcnt(8)
    // waits K-tile 0's 8 loads, leaves K-tile 1's 8 in flight.
    STAGE(Agp, As[0], 0, 0);
    STAGE(Agp, As[0], 0, 1);
    STAGE(Bgp, Bs[0], 0, 0);
    STAGE(Bgp, Bs[0], 0, 1);
    STAGE(Agp, As[1], 1, 0);
    STAGE(Agp, As[1], 1, 1);
    STAGE(Bgp, Bs[1], 1, 0);
    STAGE(Bgp, Bs[1], 1, 1);
    VMC8();
    BAR();

    #pragma unroll 1
    for (int it = 0; it < 16; ++it) {
        const int k2 = 2 * it;
        const bool pf = (it < 15);
        // p1 — Q(0,0) buf0 (reads A.h0, B.h0 only)
        RD_A(0, 0);
        RD_B(0, 0, bv0);
        BAR(); LGKM0();
        MFMAQ(0, 0, bv0);
        BAR();
        // p2 — Q(0,1) buf0 (reads B.h1); stage A0.h0+B0.h0(k+2) into regions
        // whose only read was p1 (barrier-separated).
        RD_B(0, 1, bv1);
        if (pf) { STAGE(Agp, As[0], k2 + 2, 0); STAGE(Bgp, Bs[0], k2 + 2, 0); }
        BAR(); LGKM0();
        MFMAQ(0, 1, bv1);
        BAR();
        // p3 — Q(1,1) buf0 (reads A.h1); stage B0.h1(k+2) (read at p2).
        RD_A(0, 1);
        if (pf) STAGE(Bgp, Bs[0], k2 + 2, 1);
        BAR(); LGKM0();
        MFMAQ(1, 1, bv1);
        BAR();
        // p4 — Q(1,0) buf0 (bv0 registers reused, NO ds_read); stage
        // A0.h1(k+2) (read at p3). vmcnt(8) leaves p6..p8-equivalent stages
        // (here p2:4 + p3:2 + p4:2 = 8) in flight => buf1(k+1) fully landed.
        if (pf) STAGE(Agp, As[0], k2 + 2, 1);
        BAR();
        MFMAQ(1, 0, bv0);
        if (pf) { VMC8(); } else { VMC0(); }
        BAR();
        // p5 — Q(0,0) buf1
        RD_A(1, 0);
        RD_B(1, 0, bv0);
        BAR(); LGKM0();
        MFMAQ(0, 0, bv0);
        BAR();
        // p6 — Q(0,1) buf1; stage A1.h0+B1.h0(k+3)
        RD_B(1, 1, bv1);
        if (pf) { STAGE(Agp, As[1], k2 + 3, 0); STAGE(Bgp, Bs[1], k2 + 3, 0); }
        BAR(); LGKM0();
        MFMAQ(0, 1, bv1);
        BAR();
        // p7 — Q(1,1) buf1; stage B1.h1(k+3)
        RD_A(1, 1);
        if (pf) STAGE(Bgp, Bs[1], k2 + 3, 1);
        BAR(); LGKM0();
        MFMAQ(1, 1, bv1);
        BAR();
        // p8 — Q(1,0) buf1 (bv0 reused); stage A1.h1(k+3); vmcnt(8) leaves
        // p6:4+p7:2+p8:2 in flight => buf0(k+2) fully landed for next p1.
        if (pf) STAGE(Agp, As[1], k2 + 3, 1);
        BAR();
        MFMAQ(1, 0, bv0);
        if (pf) { VMC8(); }
        BAR();
    }

    float* P = (z == 0) ? P0 : ((z == 1) ? P1 : ((z == 2) ? P2 : P3));
    #pragma unroll
    for (int m = 0; m < 8; ++m) {
        const int prow = p0 + ((m >> 2) << 7) + wr * 64 + (m & 3) * 16 + quad * 4;
        #pragma unroll
        for (int n = 0; n < 4; ++n) {
            const int qcol = q0 + ((n >> 1) << 7) + wc * 32 + (n & 1) * 16 + m16;
            #pragma unroll
            for (int r = 0; r < 4; ++r)
                P[(size_t)(prow + r) * NQ + qcol] = acc[m][n][r];
        }
    }
}

// ---------------------------------------------------------------------------
// Stage 2 FALLBACK (r9, proven): split-K=2 GEMM, 512 blocks x 256 thr.
// ---------------------------------------------------------------------------
__global__ __launch_bounds__(256, 2) void gemm_split(
    const ushort_t* __restrict__ Ab, const ushort_t* __restrict__ Bb,
    const float* __restrict__ sp, float* __restrict__ scaleBuf,
    float* __restrict__ P0, float* __restrict__ P1)
{
    __shared__ ushort_t Ls[2][128 * 64];
    __shared__ ushort_t Rs[2][128 * 64];
    __shared__ float red[4];

    const int tid  = threadIdx.x;
    const int lane = tid & 63;
    const int wv   = tid >> 6;
    const int wr   = wv >> 1;
    const int wc   = wv & 1;
    const int quad = lane >> 4;
    const int m16  = lane & 15;

    if (blockIdx.x == 0) {
        float v = 0.f;
        #pragma unroll
        for (int i = 0; i < 16; ++i) v += sp[tid + i * 256];
        #pragma unroll
        for (int off = 32; off > 0; off >>= 1)
            v += __shfl_down(v, off, 64);
        if (lane == 0) red[wv] = v;
        __syncthreads();
        if (tid == 0) {
            float s = (red[0] + red[1]) + (red[2] + red[3]);
            scaleBuf[0] = sqrtf(0.1f / (s * (1.0f / 4096.0f) + 1e-6f));
        }
    }

    const int id  = blockIdx.x;
    const int xcd = id & 7;
    const int j5  = id >> 3;
    const int z   = j5 & 1;
    const int t   = j5 >> 1;
    const int pt  = ((xcd >> 1) << 2) + (t >> 3);
    const int qt  = ((xcd & 1) << 3) + (t & 7);

    const int p0 = pt * 128;
    const int q0 = qt * 128;
    const int kbase = z * (KT / 2);
    const int ldsbase = wv * 512;

    const ushort_t* gaP[4];
    const ushort_t* gbP[4];
    #pragma unroll
    for (int rr = 0; rr < 4; ++rr) {
        const int c   = rr * 256 + tid;
        const int row = c >> 3;
        const int kk8 = (c & 7) ^ (row & 7);
        gaP[rr] = Ab + (size_t)(p0 + row) * KT + kbase + kk8 * 8;
        gbP[rr] = Bb + (size_t)(q0 + row) * KT + kbase + kk8 * 8;
    }

    f32x4 acc[4][4] = {};

    auto stageF = [&](int buf) {
        #pragma unroll
        for (int rr = 0; rr < 4; ++rr) {
            async16(gaP[rr], &Ls[buf][rr * 2048 + ldsbase]);
            async16(gbP[rr], &Rs[buf][rr * 2048 + ldsbase]);
            gaP[rr] += 64;
            gbP[rr] += 64;
        }
    };
    auto computeF = [&](int buf) {
        #pragma unroll
        for (int ks = 0; ks < 2; ++ks) {
            bf16x8 afl[4], bfr[4];
            #pragma unroll
            for (int i = 0; i < 4; ++i) {
                const int row  = wr * 64 + i * 16 + m16;
                const int slot = (ks * 4 + quad) ^ (row & 7);
                afl[i] = *(const bf16x8*)&Ls[buf][row * 64 + slot * 8];
            }
            #pragma unroll
            for (int jj = 0; jj < 4; ++jj) {
                const int row  = wc * 64 + jj * 16 + m16;
                const int slot = (ks * 4 + quad) ^ (row & 7);
                bfr[jj] = *(const bf16x8*)&Rs[buf][row * 64 + slot * 8];
            }
            #pragma unroll
            for (int i = 0; i < 4; ++i)
                #pragma unroll
                for (int jj = 0; jj < 4; ++jj)
                    acc[i][jj] = __builtin_amdgcn_mfma_f32_16x16x32_bf16(
                        afl[i], bfr[jj], acc[i][jj], 0, 0, 0);
        }
    };

    constexpr int NIT = (KT / 2) / 64;
    stageF(0);
    for (int kt2 = 0; kt2 < NIT / 2; ++kt2) {
        __syncthreads();
        stageF(1);
        computeF(0);
        __syncthreads();
        if (kt2 + 1 < NIT / 2)
            stageF(0);
        computeF(1);
    }

    float* P = z ? P1 : P0;
    #pragma unroll
    for (int i = 0; i < 4; ++i) {
        const int prow = p0 + wr * 64 + i * 16 + quad * 4;
        #pragma unroll
        for (int jj = 0; jj < 4; ++jj) {
            const int qcol = q0 + wc * 64 + jj * 16 + m16;
            #pragma unroll
            for (int r2 = 0; r2 < 4; ++r2)
                P[(size_t)(prow + r2) * NQ + qcol] = acc[i][jj][r2];
        }
    }
}

// ---------------------------------------------------------------------------
// Stage 3: Out = clip(W + scale*(P0+P1+P2+P3), -2, 2); P0 lives in d_out.
// ---------------------------------------------------------------------------
__global__ __launch_bounds__(256) void merge_out4(
    const float* __restrict__ W, const float* __restrict__ P1,
    const float* __restrict__ P2, const float* __restrict__ P3,
    const float* __restrict__ scaleBuf, float* __restrict__ Out)
{
    const float scale = scaleBuf[0];
    const size_t i4 = (size_t)blockIdx.x * 256 + threadIdx.x;
    float4 w = ((const float4*)W)[i4];
    float4 a = ((const float4*)Out)[i4];
    float4 b = ((const float4*)P1)[i4];
    float4 c = ((const float4*)P2)[i4];
    float4 d = ((const float4*)P3)[i4];
    float4 o;
    o.x = fminf(fmaxf(fmaf(scale, (a.x + b.x) + (c.x + d.x), w.x), -2.f), 2.f);
    o.y = fminf(fmaxf(fmaf(scale, (a.y + b.y) + (c.y + d.y), w.y), -2.f), 2.f);
    o.z = fminf(fmaxf(fmaf(scale, (a.z + b.z) + (c.z + d.z), w.z), -2.f), 2.f);
    o.w = fminf(fmaxf(fmaf(scale, (a.w + b.w) + (c.w + d.w), w.w), -2.f), 2.f);
    ((float4*)Out)[i4] = o;
}

__global__ __launch_bounds__(256) void merge_out2(
    const float* __restrict__ W, const float* __restrict__ P1,
    const float* __restrict__ scaleBuf, float* __restrict__ Out)
{
    const float scale = scaleBuf[0];
    const size_t i4 = (size_t)blockIdx.x * 256 + threadIdx.x;
    float4 w = ((const float4*)W)[i4];
    float4 a = ((const float4*)Out)[i4];
    float4 c = ((const float4*)P1)[i4];
    float4 o;
    o.x = fminf(fmaxf(fmaf(scale, a.x + c.x, w.x), -2.f), 2.f);
    o.y = fminf(fmaxf(fmaf(scale, a.y + c.y, w.y), -2.f), 2.f);
    o.z = fminf(fmaxf(fmaf(scale, a.z + c.z, w.z), -2.f), 2.f);
    o.w = fminf(fmaxf(fmaf(scale, a.w + c.w, w.w), -2.f), 2.f);
    ((float4*)Out)[i4] = o;
}

extern "C" void kernel_launch(void* const* d_in, const int* in_sizes, int n_in,
                              void* d_out, int out_size, void* d_ws, size_t ws_size,
                              hipStream_t stream) {
    const float* pre  = (const float*)d_in[0];
    const float* post = (const float*)d_in[1];
    const float* W    = (const float*)d_in[2];
    const float* mAp  = (const float*)d_in[3];
    const float* mAm  = (const float*)d_in[4];
    float* out = (float*)d_out;

    const size_t AB = (size_t)NP * KT * 2;   // 33.55 MB per panel
    const size_t PB = (size_t)NP * NQ * 4;   // 16.78 MB per partial

    char* ws = (char*)d_ws;
    float* partials = (float*)ws;                       // 16 KB (4096 slots)
    float* scaleBuf = (float*)(ws + 16384);
    ushort_t* Ab = (ushort_t*)(ws + 32768);
    ushort_t* Bb = (ushort_t*)(ws + 32768 + AB);
    float* P1 = (float*)(ws + 32768 + 2 * AB);
    float* P2 = (float*)(ws + 32768 + 2 * AB + PB);
    float* P3 = (float*)(ws + 32768 + 2 * AB + 2 * PB);

    stage_traces<<<dim3((TB * NP + TB * NQ) / 16), dim3(256), 0, stream>>>(
        pre, post, mAp, mAm, Ab, Bb, partials);

    if (ws_size >= 32768 + 2 * AB + 3 * PB) {
        gemm8<<<dim3(256), dim3(512), 0, stream>>>(
            Ab, Bb, partials, scaleBuf, out, P1, P2, P3);
        merge_out4<<<dim3(NP * NQ / 1024), dim3(256), 0, stream>>>(
            W, P1, P2, P3, scaleBuf, out);
    } else {
        gemm_split<<<dim3(512), dim3(256), 0, stream>>>(
            Ab, Bb, partials, scaleBuf, out, P1);
        merge_out2<<<dim3(NP * NQ / 1024), dim3(256), 0, stream>>>(
            W, P1, scaleBuf, out);
    }
}